// Round 15
// baseline (972.353 us; speedup 1.0000x reference)
//
#include <hip/hip_runtime.h>
#include <math.h>
#include <limits.h>

#define DF 512
#define DH 64
#define DL 16
#define NC 10
#define NF 10
#define KPROP 10

#define BSH 7                  // bucket shift: 128 nodes per bucket
#define BW  (1 << BSH)
#define MAXB 1024
#define TILE 16384

__device__ __forceinline__ float softplus_(float x){
  return fmaxf(x, 0.0f) + log1pf(expf(-fabsf(x)));
}

__device__ __forceinline__ unsigned int f2bf_(float f){
  unsigned int u = __float_as_uint(f);
  return (u + 0x7FFFu + ((u >> 16) & 1u)) >> 16;          // RNE
}
__device__ __forceinline__ unsigned int pack2bf_(float lo, float hi){
  return f2bf_(lo) | (f2bf_(hi) << 16);
}

// -------- GEMM1 fused with z-projection: z = relu(x@W1+b1) @ W2 + b2 --------
// (proven config: 64x64 tile, 4x4 microtile, BK=32, 124us, 36 VGPR — FINAL)
#define BM 64
#define BN 64
#define BK 32
__global__ __launch_bounds__(256) void k_gemm1z(const float* __restrict__ x,
    const float* __restrict__ W1, const float* __restrict__ b1,
    const float* __restrict__ W2, const float* __restrict__ b2,
    float* __restrict__ z, int N)
{
  __shared__ float smem[2*BK*(BM+4)];           // At | Bs, later overlaid by hs[64][68]
  float (*At)[BM+4] = (float(*)[BM+4])smem;
  float (*Bs)[BN+4] = (float(*)[BN+4])(smem + BK*(BM+4));
  __shared__ float W2s[DH][DL];
  __shared__ float b2s[DL];
  const int tid = threadIdx.x;
  for (int i = tid; i < DH*DL; i += 256) W2s[i>>4][i&15] = W2[i];
  if (tid < DL) b2s[tid] = b2[tid];
  const int tx = tid & 15, ty = tid >> 4;
  const int row0 = blockIdx.x * BM;
  float acc[4][4] = {};
  for (int k0 = 0; k0 < DF; k0 += BK) {
    #pragma unroll
    for (int i = 0; i < 2; ++i) {
      int idx = tid + i*256;
      int r  = idx >> 3;
      int kk = (idx & 7) << 2;
      int row = row0 + r;
      float4 va = make_float4(0.f,0.f,0.f,0.f);
      if (row < N) va = *(const float4*)&x[(size_t)row*DF + k0 + kk];
      At[kk+0][r]=va.x; At[kk+1][r]=va.y; At[kk+2][r]=va.z; At[kk+3][r]=va.w;
      int r2 = idx >> 4;
      int c4 = (idx & 15) << 2;
      float4 vb = *(const float4*)&W1[(size_t)(k0+r2)*DH + c4];
      Bs[r2][c4+0]=vb.x; Bs[r2][c4+1]=vb.y; Bs[r2][c4+2]=vb.z; Bs[r2][c4+3]=vb.w;
    }
    __syncthreads();
    #pragma unroll
    for (int kk = 0; kk < BK; ++kk) {
      float4 av = *(const float4*)&At[kk][ty<<2];
      float4 bv = *(const float4*)&Bs[kk][tx<<2];
      float a4[4]={av.x,av.y,av.z,av.w};
      float b4[4]={bv.x,bv.y,bv.z,bv.w};
      #pragma unroll
      for (int i=0;i<4;++i)
        #pragma unroll
        for (int j=0;j<4;++j) acc[i][j] = fmaf(a4[i], b4[j], acc[i][j]);
    }
    __syncthreads();
  }
  // epilogue: h tile -> LDS (overlay), then z = h@W2+b2
  float4 bias = ((const float4*)b1)[tx];
  float bias4[4] = {bias.x, bias.y, bias.z, bias.w};
  float (*hs)[BM+4] = (float(*)[BM+4])smem;
  #pragma unroll
  for (int i=0;i<4;++i){
    #pragma unroll
    for (int j=0;j<4;++j)
      hs[(ty<<2)+i][(tx<<2)+j] = fmaxf(acc[i][j] + bias4[j], 0.0f);
  }
  __syncthreads();
  int row = tid >> 2, lg = tid & 3;
  float4 zacc = ((const float4*)b2s)[lg];
  #pragma unroll 8
  for (int k = 0; k < DH; ++k){
    float hv = hs[row][k];
    float4 wv = *(const float4*)&W2s[k][lg<<2];
    zacc.x = fmaf(hv, wv.x, zacc.x);
    zacc.y = fmaf(hv, wv.y, zacc.y);
    zacc.z = fmaf(hv, wv.z, zacc.z);
    zacc.w = fmaf(hv, wv.w, zacc.w);
  }
  int grow = row0 + row;
  if (grow < N) ((float4*)z)[(size_t)grow*4 + lg] = zacc;
}

// -------- radial flows: one thread per (node, class) --------
// emits x0 (fp32), y0 = 0.1*dinv*x0 (fp32), c0 = dinv*x0 (bf16)
__global__ __launch_bounds__(256) void k_flow2(const float* __restrict__ z,
    const float* __restrict__ pc, const float* __restrict__ z0g,
    const float* __restrict__ apg, const float* __restrict__ fbg,
    const float* __restrict__ dinv,
    float* __restrict__ x0, unsigned short* __restrict__ c0b,
    float* __restrict__ y0, int N)
{
  __shared__ float z0s[NF][NC][DL];
  __shared__ float alps[NF][NC];
  __shared__ float bhs[NF][NC];
  __shared__ float lpc[NC];
  int tid = threadIdx.x;
  for (int i = tid; i < NF*NC*DL; i += 256)
    z0s[(i>>4)/NC][(i>>4)%NC][i&15] = z0g[i];
  if (tid < NF*NC){
    int l = tid/NC, c = tid%NC;
    float al = softplus_(apg[tid]);
    alps[l][c] = al;
    bhs[l][c]  = -al + softplus_(fbg[tid]);
  }
  if (tid < NC) lpc[tid] = __logf(pc[tid]);
  __syncthreads();

  int idx = blockIdx.x*256 + tid;
  int n = idx >> 4, c = idx & 15;
  if (n >= N) return;
  float dn = dinv[n];
  if (c >= NC){ x0[idx] = 0.f; c0b[idx] = 0; y0[idx] = 0.f; return; }

  float zz[DL];
  const float4* z4 = (const float4*)z;
  #pragma unroll
  for (int q=0; q<4; ++q){
    float4 v = z4[(size_t)n*4 + q];
    zz[q*4+0]=v.x; zz[q*4+1]=v.y; zz[q*4+2]=v.z; zz[q*4+3]=v.w;
  }
  const float NEGHALFD_LOG2PI = -14.703016531274762f;  // -8*log(2*pi)
  const float LOGSCALE        =  20.248193975754326f;  //  8*log(4*pi)
  float sld = 0.f;
  #pragma unroll 1
  for (int l=0; l<NF; ++l){
    float al = alps[l][c], bhat = bhs[l][c];
    float dz[DL]; float r2 = 0.f;
    #pragma unroll
    for (int d=0; d<DL; ++d){ float t = zz[d] - z0s[l][c][d]; dz[d]=t; r2 = fmaf(t,t,r2); }
    float r  = sqrtf(r2);
    float hh = 1.0f/(al + r);
    float bh = bhat*hh;
    #pragma unroll
    for (int d=0; d<DL; ++d) zz[d] = fmaf(bh, dz[d], zz[d]);
    sld += 15.0f*__logf(1.0f + bh) + __logf(1.0f + bh - bhat*r*hh*hh);
  }
  float q2 = 0.f;
  #pragma unroll
  for (int d=0; d<DL; ++d) q2 = fmaf(zz[d], zz[d], q2);
  float v = -0.5f*q2 + NEGHALFD_LOG2PI + sld + lpc[c] + LOGSCALE;
  v = fminf(fmaxf(v, -30.f), 30.f);
  float xv = __expf(v);
  x0[idx] = xv;
  float cv = dn*xv;
  c0b[idx] = (unsigned short)f2bf_(cv);
  y0[idx]  = 0.1f*cv;
}

// ---------------- bucketed CSR construction ----------------
__global__ __launch_bounds__(256) void k_bhist(const int* __restrict__ dst,
    int* __restrict__ bCnt, int E, int B)
{
  __shared__ int hh[MAXB];
  int tid = threadIdx.x;
  for (int b = tid; b < B; b += 256) hh[b] = 0;
  __syncthreads();
  for (int i = blockIdx.x*256 + tid; i < E; i += gridDim.x*256)
    atomicAdd(&hh[dst[i] >> BSH], 1);
  __syncthreads();
  for (int b = tid; b < B; b += 256) if (hh[b]) atomicAdd(&bCnt[b], hh[b]);
}

// one-block exclusive scan for n <= 1024 (handles in==out); optional total at out[n]
__global__ __launch_bounds__(256) void k_scan_small(const int* __restrict__ in,
    int* __restrict__ out, int n, int writeTotal)
{
  __shared__ int sd[1024];
  int tid = threadIdx.x;
  int orig[4];
  #pragma unroll
  for (int j = 0; j < 4; ++j){
    int i = tid + j*256;
    orig[j] = (i < n) ? in[i] : 0;
    sd[i] = orig[j];
  }
  __syncthreads();
  for (int ofs = 1; ofs < 1024; ofs <<= 1){
    int vals[4];
    #pragma unroll
    for (int j = 0; j < 4; ++j){
      int i = tid + j*256;
      vals[j] = (i >= ofs) ? sd[i-ofs] : 0;
    }
    __syncthreads();
    #pragma unroll
    for (int j = 0; j < 4; ++j) sd[tid + j*256] += vals[j];
    __syncthreads();
  }
  #pragma unroll
  for (int j = 0; j < 4; ++j){
    int i = tid + j*256;
    if (i < n) out[i] = sd[i] - orig[j];    // exclusive
  }
  if (writeTotal && tid == 0) out[n] = sd[n-1];
}

__global__ __launch_bounds__(256) void k_bscatter(const int* __restrict__ src,
    const int* __restrict__ dst, const int* __restrict__ bOff,
    int* __restrict__ bCur, int* __restrict__ bp, int E, int B)
{
  __shared__ int hc[MAXB];
  __shared__ int hb[MAXB];
  int tid = threadIdx.x;
  int base = blockIdx.x * TILE;
  int lim  = base + TILE; if (lim > E) lim = E;
  for (int b = tid; b < B; b += 256) hc[b] = 0;
  __syncthreads();
  for (int i = base + tid; i < lim; i += 256)
    atomicAdd(&hc[dst[i] >> BSH], 1);
  __syncthreads();
  for (int b = tid; b < B; b += 256){
    int c = hc[b];
    hb[b] = c ? atomicAdd(&bCur[b], c) : 0;
    hc[b] = 0;
  }
  __syncthreads();
  for (int i = base + tid; i < lim; i += 256){
    int d = dst[i];
    int b = d >> BSH;
    int pos = bOff[b] + hb[b] + atomicAdd(&hc[b], 1);
    bp[pos] = (src[i] << BSH) | (d & (BW-1));
  }
}

// per-bucket in-degree count (+1 self loop) fused with dinv/dinv2 and the
// capped-degree histogram for the divergence-reducing node permutation.
__global__ __launch_bounds__(256) void k_bdeg(const int* __restrict__ bp,
    const int* __restrict__ bOff, int* __restrict__ deg,
    float* __restrict__ dinv, float* __restrict__ dinv2,
    int* __restrict__ dH, int N)
{
  __shared__ int cur[BW];
  __shared__ int lh[256];
  int tid = threadIdx.x;
  int b = blockIdx.x;
  if (tid < BW) cur[tid] = 0;
  lh[tid] = 0;
  __syncthreads();
  int s = bOff[b], e = bOff[b+1];
  for (int i = s + tid; i < e; i += 256)
    atomicAdd(&cur[bp[i] & (BW-1)], 1);
  __syncthreads();
  int node = (b << BSH) + tid;
  if (tid < BW && node < N){
    int d = cur[tid] + 1;                 // +1 self loop
    deg[node] = d;
    float dv = 1.0f / sqrtf((float)d);
    dinv[node]  = dv;
    dinv2[node] = dv*dv;
    int dc = d < 255 ? d : 255;
    atomicAdd(&lh[dc], 1);
  }
  __syncthreads();
  if (lh[tid]) atomicAdd(&dH[tid], lh[tid]);
}

// scatter node ids by capped degree -> perm (within-bucket order arbitrary;
// numerically irrelevant: per-node accumulation order is unchanged)
__global__ __launch_bounds__(256) void k_permscatter(const int* __restrict__ deg,
    const int* __restrict__ dHo, int* __restrict__ dHc,
    int* __restrict__ perm, int N)
{
  int n = blockIdx.x*256 + threadIdx.x;
  if (n >= N) return;
  int d = deg[n];
  int dc = d < 255 ? d : 255;
  int pos = dHo[dc] + atomicAdd(&dHc[dc], 1);
  perm[pos] = n;
}

__global__ __launch_bounds__(256) void k_scan_part(const int* __restrict__ deg,
    int* __restrict__ part, int N){
  __shared__ int sd[256];
  int base = blockIdx.x*1024;
  int tid = threadIdx.x;
  int s = 0;
  #pragma unroll
  for (int i=0;i<4;++i){ int idx = base + tid*4 + i; if (idx < N) s += deg[idx]; }
  sd[tid] = s; __syncthreads();
  for (int ofs=128; ofs>0; ofs>>=1){ if (tid<ofs) sd[tid]+=sd[tid+ofs]; __syncthreads(); }
  if (tid==0) part[blockIdx.x] = sd[0];
}

__global__ __launch_bounds__(256) void k_scan_final(const int* __restrict__ deg,
    const int* __restrict__ part, int* __restrict__ off, int N, int E)
{
  __shared__ int sc[256];
  int base = blockIdx.x*1024;
  int tid = threadIdx.x;
  int v[4]; int s = 0;
  #pragma unroll
  for (int i=0;i<4;++i){ int idx = base + tid*4 + i; v[i] = (idx<N)?deg[idx]:0; s += v[i]; }
  sc[tid] = s; __syncthreads();
  for (int ofs=1; ofs<256; ofs<<=1){
    int t = (tid>=ofs) ? sc[tid-ofs] : 0;
    __syncthreads();
    sc[tid] += t;
    __syncthreads();
  }
  int ex = sc[tid] - s + part[blockIdx.x];
  #pragma unroll
  for (int i=0;i<4;++i){
    int idx = base + tid*4 + i;
    if (idx < N){
      off[idx] = ex;
      if (idx == N-1) off[N] = ex + v[i];
      ex += v[i];
    }
  }
}

// place self edge (slot 0) + src ints at CSR positions
__global__ __launch_bounds__(256) void k_place(const int* __restrict__ bp,
    const int* __restrict__ bOff, const int* __restrict__ off,
    int* __restrict__ csr, int N)
{
  __shared__ int cur[BW];
  int tid = threadIdx.x;
  int b = blockIdx.x;
  int node0 = b << BSH;
  if (tid < BW){
    cur[tid] = 1;                                 // slot 0 reserved for self
    int node = node0 + tid;
    if (node < N) csr[off[node]] = node;
  }
  __syncthreads();
  int s = bOff[b], e = bOff[b+1];
  for (int i = s + tid; i < e; i += 256){
    int v  = bp[i];
    int dl = v & (BW-1);
    int sn = v >> BSH;
    int d  = node0 + dl;
    int p  = off[d] + atomicAdd(&cur[dl], 1);
    csr[p] = sn;
  }
}

// ---- canonicalize segment order (stable value-rank via shuffles) ----
__global__ __launch_bounds__(256) void k_rank(int* __restrict__ csr,
    const int* __restrict__ off, int N)
{
  int wid  = (blockIdx.x*256 + threadIdx.x) >> 6;
  int lane = threadIdx.x & 63;
  if (wid >= N) return;
  int s = off[wid], e = off[wid+1];
  int d = e - s;
  if (d <= 1) return;
  if (d <= 64){
    int v = (lane < d) ? csr[s+lane] : INT_MAX;
    int rank = 0;
    for (int j = 0; j < d; ++j){
      int bv = __shfl(v, j);
      rank += (bv < v) || (bv == v && j < lane);
    }
    if (lane < d) csr[s+rank] = v;
  } else if (d <= 256){
    int v0 = (lane      < d) ? csr[s+lane      ] : INT_MAX;
    int v1 = (lane+64   < d) ? csr[s+lane+64   ] : INT_MAX;
    int v2 = (lane+128  < d) ? csr[s+lane+128  ] : INT_MAX;
    int v3 = (lane+192  < d) ? csr[s+lane+192  ] : INT_MAX;
    int r0=0,r1=0,r2=0,r3=0;
    for (int j = 0; j < d; ++j){
      int slot = j >> 6, jl = j & 63;
      int bv = (slot==0) ? __shfl(v0,jl) : (slot==1) ? __shfl(v1,jl)
             : (slot==2) ? __shfl(v2,jl) : __shfl(v3,jl);
      r0 += (bv < v0) || (bv == v0 && j < lane);
      r1 += (bv < v1) || (bv == v1 && j < lane+64);
      r2 += (bv < v2) || (bv == v2 && j < lane+128);
      r3 += (bv < v3) || (bv == v3 && j < lane+192);
    }
    if (lane      < d) csr[s+r0]=v0;
    if (lane+64   < d) csr[s+r1]=v1;
    if (lane+128  < d) csr[s+r2]=v2;
    if (lane+192  < d) csr[s+r3]=v3;
  } else {
    if (lane == 0){
      for (int i = s+1; i < e; ++i){
        int key = csr[i]; int j = i-1;
        while (j >= s && csr[j] > key){ csr[j+1] = csr[j]; --j; }
        csr[j+1] = key;
      }
    }
  }
}

// ---- APPNP c-space iteration, bf16 state, degree-sorted perm: 8 thr/node ----
__global__ __launch_bounds__(256) void k_prop(const uint4* __restrict__ cin,
    const float* __restrict__ y0, const float* __restrict__ dinv2,
    uint4* __restrict__ cout, const int* __restrict__ csr,
    const int* __restrict__ off, const int* __restrict__ perm, int N)
{
  int t = blockIdx.x*256 + threadIdx.x;
  int g = t >> 3, sub = t & 7, qh = sub >> 2, part = sub & 3;
  if (g >= N) return;
  int n = perm[g];
  int s = off[n], e = off[n+1], d = e - s;
  int lo = s + ((d*part) >> 2);
  int hi = s + ((d*(part+1)) >> 2);
  float a[8] = {0.f,0.f,0.f,0.f,0.f,0.f,0.f,0.f};
  float b[8] = {0.f,0.f,0.f,0.f,0.f,0.f,0.f,0.f};
  int i = lo;
  for (; i+2 <= hi; i += 2){
    int s0 = csr[i], s1 = csr[i+1];
    uint4 u0 = cin[(size_t)s0*2 + qh];
    uint4 u1 = cin[(size_t)s1*2 + qh];
    a[0] += __uint_as_float(u0.x << 16); a[1] += __uint_as_float(u0.x & 0xFFFF0000u);
    a[2] += __uint_as_float(u0.y << 16); a[3] += __uint_as_float(u0.y & 0xFFFF0000u);
    a[4] += __uint_as_float(u0.z << 16); a[5] += __uint_as_float(u0.z & 0xFFFF0000u);
    a[6] += __uint_as_float(u0.w << 16); a[7] += __uint_as_float(u0.w & 0xFFFF0000u);
    b[0] += __uint_as_float(u1.x << 16); b[1] += __uint_as_float(u1.x & 0xFFFF0000u);
    b[2] += __uint_as_float(u1.y << 16); b[3] += __uint_as_float(u1.y & 0xFFFF0000u);
    b[4] += __uint_as_float(u1.z << 16); b[5] += __uint_as_float(u1.z & 0xFFFF0000u);
    b[6] += __uint_as_float(u1.w << 16); b[7] += __uint_as_float(u1.w & 0xFFFF0000u);
  }
  if (i < hi){
    uint4 u0 = cin[(size_t)csr[i]*2 + qh];
    a[0] += __uint_as_float(u0.x << 16); a[1] += __uint_as_float(u0.x & 0xFFFF0000u);
    a[2] += __uint_as_float(u0.y << 16); a[3] += __uint_as_float(u0.y & 0xFFFF0000u);
    a[4] += __uint_as_float(u0.z << 16); a[5] += __uint_as_float(u0.z & 0xFFFF0000u);
    a[6] += __uint_as_float(u0.w << 16); a[7] += __uint_as_float(u0.w & 0xFFFF0000u);
  }
  float v[8];
  #pragma unroll
  for (int j = 0; j < 8; ++j){
    float t2 = a[j] + b[j];
    t2 += __shfl_xor(t2, 1, 4);
    t2 += __shfl_xor(t2, 2, 4);
    v[j] = t2;
  }
  if (part == 0){
    float w9 = 0.9f * dinv2[n];
    const float4* y4 = (const float4*)y0;
    float4 ya = y4[(size_t)n*4 + qh*2];
    float4 yb = y4[(size_t)n*4 + qh*2 + 1];
    float o0 = fmaf(w9, v[0], ya.x), o1 = fmaf(w9, v[1], ya.y);
    float o2 = fmaf(w9, v[2], ya.z), o3 = fmaf(w9, v[3], ya.w);
    float o4 = fmaf(w9, v[4], yb.x), o5 = fmaf(w9, v[5], yb.y);
    float o6 = fmaf(w9, v[6], yb.z), o7 = fmaf(w9, v[7], yb.w);
    uint4 w;
    w.x = pack2bf_(o0, o1); w.y = pack2bf_(o2, o3);
    w.z = pack2bf_(o4, o5); w.w = pack2bf_(o6, o7);
    cout[(size_t)n*2 + qh] = w;
  }
}

// ---- last iteration fused with alpha/soft/argmax (8 thr/node, perm) ----
__global__ __launch_bounds__(256) void k_prop_final(const uint4* __restrict__ cin,
    const float* __restrict__ x0, const float* __restrict__ dinv,
    const int* __restrict__ csr, const int* __restrict__ off,
    const int* __restrict__ perm, float* __restrict__ out, int N)
{
  int t = blockIdx.x*256 + threadIdx.x;
  int g = t >> 3, sub = t & 7, qh = sub >> 2, part = sub & 3;
  if (g >= N) return;
  int n = perm[g];
  int s = off[n], e = off[n+1], d = e - s;
  int lo = s + ((d*part) >> 2);
  int hi = s + ((d*(part+1)) >> 2);
  float a[8] = {0.f,0.f,0.f,0.f,0.f,0.f,0.f,0.f};
  float b[8] = {0.f,0.f,0.f,0.f,0.f,0.f,0.f,0.f};
  int i = lo;
  for (; i+2 <= hi; i += 2){
    int s0 = csr[i], s1 = csr[i+1];
    uint4 u0 = cin[(size_t)s0*2 + qh];
    uint4 u1 = cin[(size_t)s1*2 + qh];
    a[0] += __uint_as_float(u0.x << 16); a[1] += __uint_as_float(u0.x & 0xFFFF0000u);
    a[2] += __uint_as_float(u0.y << 16); a[3] += __uint_as_float(u0.y & 0xFFFF0000u);
    a[4] += __uint_as_float(u0.z << 16); a[5] += __uint_as_float(u0.z & 0xFFFF0000u);
    a[6] += __uint_as_float(u0.w << 16); a[7] += __uint_as_float(u0.w & 0xFFFF0000u);
    b[0] += __uint_as_float(u1.x << 16); b[1] += __uint_as_float(u1.x & 0xFFFF0000u);
    b[2] += __uint_as_float(u1.y << 16); b[3] += __uint_as_float(u1.y & 0xFFFF0000u);
    b[4] += __uint_as_float(u1.z << 16); b[5] += __uint_as_float(u1.z & 0xFFFF0000u);
    b[6] += __uint_as_float(u1.w << 16); b[7] += __uint_as_float(u1.w & 0xFFFF0000u);
  }
  if (i < hi){
    uint4 u0 = cin[(size_t)csr[i]*2 + qh];
    a[0] += __uint_as_float(u0.x << 16); a[1] += __uint_as_float(u0.x & 0xFFFF0000u);
    a[2] += __uint_as_float(u0.y << 16); a[3] += __uint_as_float(u0.y & 0xFFFF0000u);
    a[4] += __uint_as_float(u0.z << 16); a[5] += __uint_as_float(u0.z & 0xFFFF0000u);
    a[6] += __uint_as_float(u0.w << 16); a[7] += __uint_as_float(u0.w & 0xFFFF0000u);
  }
  float v[8];
  #pragma unroll
  for (int j = 0; j < 8; ++j){
    float t2 = a[j] + b[j];
    t2 += __shfl_xor(t2, 1, 4);
    t2 += __shfl_xor(t2, 2, 4);
    v[j] = t2;
  }
  if (part != 0) return;

  float w9 = 0.9f * dinv[n];
  const float4* x4 = (const float4*)x0;
  float4 xa = x4[(size_t)n*4 + qh*2];
  float4 xb = x4[(size_t)n*4 + qh*2 + 1];
  float xv[8] = {xa.x, xa.y, xa.z, xa.w, xb.x, xb.y, xb.z, xb.w};
  float al[8];
  #pragma unroll
  for (int j = 0; j < 8; ++j) al[j] = fmaf(w9, v[j], fmaf(0.1f, xv[j], 1.f));

  int nv = qh ? 2 : 8;              // qh0: classes 0-7, qh1: classes 8-9
  float sv = 0.f;
  for (int j = 0; j < nv; ++j) sv += al[j];
  sv += __shfl_xor(sv, 4, 8);

  float bv = -1e30f; int bi = 999;
  for (int j = 0; j < nv; ++j){
    if (al[j] > bv){ bv = al[j]; bi = qh*8 + j; }
  }
  {
    float vo = __shfl_xor(bv, 4, 8);
    int  io  = __shfl_xor(bi, 4, 8);
    if (vo > bv || (vo == bv && io < bi)){ bv = vo; bi = io; }
  }

  float inv = 1.0f / sv;
  size_t sb = (size_t)N + (size_t)n*NC;
  for (int j = 0; j < nv; ++j) out[sb + qh*8 + j] = al[j] * inv;
  if (sub == 0) out[n] = (float)bi;
}

extern "C" void kernel_launch(void* const* d_in, const int* in_sizes, int n_in,
                              void* d_out, int out_size, void* d_ws, size_t ws_size,
                              hipStream_t stream)
{
  const float* x  = (const float*)d_in[0];
  const int*   ei = (const int*)  d_in[1];
  const float* pc = (const float*)d_in[2];
  const float* W1 = (const float*)d_in[3];
  const float* b1 = (const float*)d_in[4];
  const float* W2 = (const float*)d_in[5];
  const float* b2 = (const float*)d_in[6];
  const float* z0 = (const float*)d_in[7];
  const float* ap = (const float*)d_in[8];
  const float* fb = (const float*)d_in[9];
  float* out = (float*)d_out;

  const int N = in_sizes[0] / DF;
  const int E = in_sizes[1] / 2;
  const int* src = ei;
  const int* dst = ei + E;
  const int B = (N + BW - 1) >> BSH;

  // Workspace. region0 holds bp (E ints) during CSR build, then z (N*16 f32).
  char* ws = (char*)d_ws;
  size_t o = 0;
  size_t region0 = (size_t)E*sizeof(int);
  if ((size_t)N*DL*sizeof(float) > region0) region0 = (size_t)N*DL*sizeof(float);
  int*   bp   = (int*)  (ws + o);
  float* z    = (float*)(ws + o);
  o += region0;
  int*   csr  = (int*)  (ws + o); o += (size_t)(E+N)*sizeof(int);   // +N self edges
  float* x0   = (float*)(ws + o); o += (size_t)N*DL*sizeof(float);
  float* y0   = (float*)(ws + o); o += (size_t)N*DL*sizeof(float);
  unsigned short* c0b = (unsigned short*)(ws + o); o += (size_t)N*DL*2;
  unsigned short* cAb = (unsigned short*)(ws + o); o += (size_t)N*DL*2;
  unsigned short* cBb = (unsigned short*)(ws + o); o += (size_t)N*DL*2;
  int*   deg  = (int*)  (ws + o); o += (size_t)N*sizeof(int);
  int*   perm = (int*)  (ws + o); o += (size_t)N*sizeof(int);
  float* dinv = (float*)(ws + o); o += (size_t)N*sizeof(float);
  float* dinv2= (float*)(ws + o); o += (size_t)N*sizeof(float);
  int*   offs = (int*)  (ws + o); o += (size_t)(N+2)*sizeof(int);
  int*   part = (int*)  (ws + o); o += 4096;
  int*   bCnt = (int*)  (ws + o); o += MAXB*sizeof(int);
  int*   bOff = (int*)  (ws + o); o += (MAXB+1)*sizeof(int);
  int*   bCur = (int*)  (ws + o); o += MAXB*sizeof(int);
  int*   dH   = (int*)  (ws + o); o += 256*sizeof(int);
  int*   dHo  = (int*)  (ws + o); o += 257*sizeof(int);
  int*   dHc  = (int*)  (ws + o); o += 256*sizeof(int);

  const int TB = 256;
  int gN  = (N + TB - 1) / TB;
  int nb  = (N + 1023) / 1024;

  // Phase 1: bucketed CSR build (bp lives in region0)
  hipMemsetAsync(bCnt, 0, MAXB*sizeof(int), stream);
  hipMemsetAsync(bCur, 0, MAXB*sizeof(int), stream);
  hipMemsetAsync(dH,   0, 256*sizeof(int), stream);
  hipMemsetAsync(dHc,  0, 256*sizeof(int), stream);
  k_bhist<<<512, TB, 0, stream>>>(dst, bCnt, E, B);
  k_scan_small<<<1, TB, 0, stream>>>(bCnt, bOff, B, 1);
  k_bscatter<<<(E + TILE - 1)/TILE, TB, 0, stream>>>(src, dst, bOff, bCur, bp, E, B);
  k_bdeg<<<B, TB, 0, stream>>>(bp, bOff, deg, dinv, dinv2, dH, N);
  k_scan_small<<<1, TB, 0, stream>>>(dH, dHo, 256, 1);
  k_permscatter<<<gN, TB, 0, stream>>>(deg, dHo, dHc, perm, N);
  k_scan_part<<<nb, TB, 0, stream>>>(deg, part, N);
  k_scan_small<<<1, TB, 0, stream>>>(part, part, nb, 0);
  k_scan_final<<<nb, TB, 0, stream>>>(deg, part, offs, N, E);
  k_place<<<B, TB, 0, stream>>>(bp, bOff, offs, csr, N);
  k_rank<<<(N + 3) / 4, TB, 0, stream>>>(csr, offs, N);

  // Phase 2: encoder fused with z projection (z overwrites bp), then flows
  k_gemm1z<<<(N + BM - 1) / BM, TB, 0, stream>>>(x, W1, b1, W2, b2, z, N);
  k_flow2<<<((N*DL) + TB - 1) / TB, TB, 0, stream>>>(z, pc, z0, ap, fb, dinv,
                                                     x0, c0b, y0, N);

  // Phase 3: APPNP in bf16 c-space, degree-sorted — 9 iters + 1 fused
  int gP = ((N*8) + TB - 1) / TB;
  const unsigned short* cin = c0b;
  for (int it = 0; it < KPROP-1; ++it){
    unsigned short* cout = (it & 1) ? cBb : cAb;
    k_prop<<<gP, TB, 0, stream>>>((const uint4*)cin, y0, dinv2,
                                  (uint4*)cout, csr, offs, perm, N);
    cin = cout;
  }
  k_prop_final<<<gP, TB, 0, stream>>>((const uint4*)cin, x0, dinv,
                                      csr, offs, perm, out, N);
}

// Round 16
// 642.949 us; speedup vs baseline: 1.5123x; 1.5123x over previous
//
#include <hip/hip_runtime.h>
#include <math.h>
#include <limits.h>

#define DF 512
#define DH 64
#define DL 16
#define NC 10
#define NF 10
#define KPROP 10

#define BSH 7                  // bucket shift: 128 nodes per bucket
#define BW  (1 << BSH)
#define MAXB 1024
#define TILE 16384

__device__ __forceinline__ float softplus_(float x){
  return fmaxf(x, 0.0f) + log1pf(expf(-fabsf(x)));
}

__device__ __forceinline__ unsigned int f2bf_(float f){
  unsigned int u = __float_as_uint(f);
  return (u + 0x7FFFu + ((u >> 16) & 1u)) >> 16;          // RNE
}
__device__ __forceinline__ unsigned int pack2bf_(float lo, float hi){
  return f2bf_(lo) | (f2bf_(hi) << 16);
}

// -------- GEMM1 fused with z-projection: z = relu(x@W1+b1) @ W2 + b2 --------
// (proven config: 64x64 tile, 4x4 microtile, BK=32, 124us, 36 VGPR — FINAL)
#define BM 64
#define BN 64
#define BK 32
__global__ __launch_bounds__(256) void k_gemm1z(const float* __restrict__ x,
    const float* __restrict__ W1, const float* __restrict__ b1,
    const float* __restrict__ W2, const float* __restrict__ b2,
    float* __restrict__ z, int N)
{
  __shared__ float smem[2*BK*(BM+4)];           // At | Bs, later overlaid by hs[64][68]
  float (*At)[BM+4] = (float(*)[BM+4])smem;
  float (*Bs)[BN+4] = (float(*)[BN+4])(smem + BK*(BM+4));
  __shared__ float W2s[DH][DL];
  __shared__ float b2s[DL];
  const int tid = threadIdx.x;
  for (int i = tid; i < DH*DL; i += 256) W2s[i>>4][i&15] = W2[i];
  if (tid < DL) b2s[tid] = b2[tid];
  const int tx = tid & 15, ty = tid >> 4;
  const int row0 = blockIdx.x * BM;
  float acc[4][4] = {};
  for (int k0 = 0; k0 < DF; k0 += BK) {
    #pragma unroll
    for (int i = 0; i < 2; ++i) {
      int idx = tid + i*256;
      int r  = idx >> 3;
      int kk = (idx & 7) << 2;
      int row = row0 + r;
      float4 va = make_float4(0.f,0.f,0.f,0.f);
      if (row < N) va = *(const float4*)&x[(size_t)row*DF + k0 + kk];
      At[kk+0][r]=va.x; At[kk+1][r]=va.y; At[kk+2][r]=va.z; At[kk+3][r]=va.w;
      int r2 = idx >> 4;
      int c4 = (idx & 15) << 2;
      float4 vb = *(const float4*)&W1[(size_t)(k0+r2)*DH + c4];
      Bs[r2][c4+0]=vb.x; Bs[r2][c4+1]=vb.y; Bs[r2][c4+2]=vb.z; Bs[r2][c4+3]=vb.w;
    }
    __syncthreads();
    #pragma unroll
    for (int kk = 0; kk < BK; ++kk) {
      float4 av = *(const float4*)&At[kk][ty<<2];
      float4 bv = *(const float4*)&Bs[kk][tx<<2];
      float a4[4]={av.x,av.y,av.z,av.w};
      float b4[4]={bv.x,bv.y,bv.z,bv.w};
      #pragma unroll
      for (int i=0;i<4;++i)
        #pragma unroll
        for (int j=0;j<4;++j) acc[i][j] = fmaf(a4[i], b4[j], acc[i][j]);
    }
    __syncthreads();
  }
  // epilogue: h tile -> LDS (overlay), then z = h@W2+b2
  float4 bias = ((const float4*)b1)[tx];
  float bias4[4] = {bias.x, bias.y, bias.z, bias.w};
  float (*hs)[BM+4] = (float(*)[BM+4])smem;
  #pragma unroll
  for (int i=0;i<4;++i){
    #pragma unroll
    for (int j=0;j<4;++j)
      hs[(ty<<2)+i][(tx<<2)+j] = fmaxf(acc[i][j] + bias4[j], 0.0f);
  }
  __syncthreads();
  int row = tid >> 2, lg = tid & 3;
  float4 zacc = ((const float4*)b2s)[lg];
  #pragma unroll 8
  for (int k = 0; k < DH; ++k){
    float hv = hs[row][k];
    float4 wv = *(const float4*)&W2s[k][lg<<2];
    zacc.x = fmaf(hv, wv.x, zacc.x);
    zacc.y = fmaf(hv, wv.y, zacc.y);
    zacc.z = fmaf(hv, wv.z, zacc.z);
    zacc.w = fmaf(hv, wv.w, zacc.w);
  }
  int grow = row0 + row;
  if (grow < N) ((float4*)z)[(size_t)grow*4 + lg] = zacc;
}

// -------- radial flows: one thread per (node, class) --------
// emits x0 (fp32), y0 = 0.1*dinv*x0 (fp32), c0 = dinv*x0 (bf16)
__global__ __launch_bounds__(256) void k_flow2(const float* __restrict__ z,
    const float* __restrict__ pc, const float* __restrict__ z0g,
    const float* __restrict__ apg, const float* __restrict__ fbg,
    const float* __restrict__ dinv,
    float* __restrict__ x0, unsigned short* __restrict__ c0b,
    float* __restrict__ y0, int N)
{
  __shared__ float z0s[NF][NC][DL];
  __shared__ float alps[NF][NC];
  __shared__ float bhs[NF][NC];
  __shared__ float lpc[NC];
  int tid = threadIdx.x;
  for (int i = tid; i < NF*NC*DL; i += 256)
    z0s[(i>>4)/NC][(i>>4)%NC][i&15] = z0g[i];
  if (tid < NF*NC){
    int l = tid/NC, c = tid%NC;
    float al = softplus_(apg[tid]);
    alps[l][c] = al;
    bhs[l][c]  = -al + softplus_(fbg[tid]);
  }
  if (tid < NC) lpc[tid] = __logf(pc[tid]);
  __syncthreads();

  int idx = blockIdx.x*256 + tid;
  int n = idx >> 4, c = idx & 15;
  if (n >= N) return;
  float dn = dinv[n];
  if (c >= NC){ x0[idx] = 0.f; c0b[idx] = 0; y0[idx] = 0.f; return; }

  float zz[DL];
  const float4* z4 = (const float4*)z;
  #pragma unroll
  for (int q=0; q<4; ++q){
    float4 v = z4[(size_t)n*4 + q];
    zz[q*4+0]=v.x; zz[q*4+1]=v.y; zz[q*4+2]=v.z; zz[q*4+3]=v.w;
  }
  const float NEGHALFD_LOG2PI = -14.703016531274762f;  // -8*log(2*pi)
  const float LOGSCALE        =  20.248193975754326f;  //  8*log(4*pi)
  float sld = 0.f;
  #pragma unroll 1
  for (int l=0; l<NF; ++l){
    float al = alps[l][c], bhat = bhs[l][c];
    float dz[DL]; float r2 = 0.f;
    #pragma unroll
    for (int d=0; d<DL; ++d){ float t = zz[d] - z0s[l][c][d]; dz[d]=t; r2 = fmaf(t,t,r2); }
    float r  = sqrtf(r2);
    float hh = 1.0f/(al + r);
    float bh = bhat*hh;
    #pragma unroll
    for (int d=0; d<DL; ++d) zz[d] = fmaf(bh, dz[d], zz[d]);
    sld += 15.0f*__logf(1.0f + bh) + __logf(1.0f + bh - bhat*r*hh*hh);
  }
  float q2 = 0.f;
  #pragma unroll
  for (int d=0; d<DL; ++d) q2 = fmaf(zz[d], zz[d], q2);
  float v = -0.5f*q2 + NEGHALFD_LOG2PI + sld + lpc[c] + LOGSCALE;
  v = fminf(fmaxf(v, -30.f), 30.f);
  float xv = __expf(v);
  x0[idx] = xv;
  float cv = dn*xv;
  c0b[idx] = (unsigned short)f2bf_(cv);
  y0[idx]  = 0.1f*cv;
}

// ---------------- bucketed CSR construction ----------------
__global__ __launch_bounds__(256) void k_bhist(const int* __restrict__ dst,
    int* __restrict__ bCnt, int E, int B)
{
  __shared__ int hh[MAXB];
  int tid = threadIdx.x;
  for (int b = tid; b < B; b += 256) hh[b] = 0;
  __syncthreads();
  for (int i = blockIdx.x*256 + tid; i < E; i += gridDim.x*256)
    atomicAdd(&hh[dst[i] >> BSH], 1);
  __syncthreads();
  for (int b = tid; b < B; b += 256) if (hh[b]) atomicAdd(&bCnt[b], hh[b]);
}

// one-block exclusive scan for n <= 1024 (handles in==out); optional total at out[n]
__global__ __launch_bounds__(256) void k_scan_small(const int* __restrict__ in,
    int* __restrict__ out, int n, int writeTotal)
{
  __shared__ int sd[1024];
  int tid = threadIdx.x;
  int orig[4];
  #pragma unroll
  for (int j = 0; j < 4; ++j){
    int i = tid + j*256;
    orig[j] = (i < n) ? in[i] : 0;
    sd[i] = orig[j];
  }
  __syncthreads();
  for (int ofs = 1; ofs < 1024; ofs <<= 1){
    int vals[4];
    #pragma unroll
    for (int j = 0; j < 4; ++j){
      int i = tid + j*256;
      vals[j] = (i >= ofs) ? sd[i-ofs] : 0;
    }
    __syncthreads();
    #pragma unroll
    for (int j = 0; j < 4; ++j) sd[tid + j*256] += vals[j];
    __syncthreads();
  }
  #pragma unroll
  for (int j = 0; j < 4; ++j){
    int i = tid + j*256;
    if (i < n) out[i] = sd[i] - orig[j];    // exclusive
  }
  if (writeTotal && tid == 0) out[n] = sd[n-1];
}

__global__ __launch_bounds__(256) void k_bscatter(const int* __restrict__ src,
    const int* __restrict__ dst, const int* __restrict__ bOff,
    int* __restrict__ bCur, int* __restrict__ bp, int E, int B)
{
  __shared__ int hc[MAXB];
  __shared__ int hb[MAXB];
  int tid = threadIdx.x;
  int base = blockIdx.x * TILE;
  int lim  = base + TILE; if (lim > E) lim = E;
  for (int b = tid; b < B; b += 256) hc[b] = 0;
  __syncthreads();
  for (int i = base + tid; i < lim; i += 256)
    atomicAdd(&hc[dst[i] >> BSH], 1);
  __syncthreads();
  for (int b = tid; b < B; b += 256){
    int c = hc[b];
    hb[b] = c ? atomicAdd(&bCur[b], c) : 0;
    hc[b] = 0;
  }
  __syncthreads();
  for (int i = base + tid; i < lim; i += 256){
    int d = dst[i];
    int b = d >> BSH;
    int pos = bOff[b] + hb[b] + atomicAdd(&hc[b], 1);
    bp[pos] = (src[i] << BSH) | (d & (BW-1));
  }
}

// per-bucket in-degree count (+1 self loop) fused with dinv/dinv2
__global__ __launch_bounds__(256) void k_bdeg(const int* __restrict__ bp,
    const int* __restrict__ bOff, int* __restrict__ deg,
    float* __restrict__ dinv, float* __restrict__ dinv2, int N)
{
  __shared__ int cur[BW];
  int tid = threadIdx.x;
  int b = blockIdx.x;
  if (tid < BW) cur[tid] = 0;
  __syncthreads();
  int s = bOff[b], e = bOff[b+1];
  for (int i = s + tid; i < e; i += 256)
    atomicAdd(&cur[bp[i] & (BW-1)], 1);
  __syncthreads();
  int node = (b << BSH) + tid;
  if (tid < BW && node < N){
    int d = cur[tid] + 1;                 // +1 self loop
    deg[node] = d;
    float dv = 1.0f / sqrtf((float)d);
    dinv[node]  = dv;
    dinv2[node] = dv*dv;
  }
}

__global__ __launch_bounds__(256) void k_scan_part(const int* __restrict__ deg,
    int* __restrict__ part, int N){
  __shared__ int sd[256];
  int base = blockIdx.x*1024;
  int tid = threadIdx.x;
  int s = 0;
  #pragma unroll
  for (int i=0;i<4;++i){ int idx = base + tid*4 + i; if (idx < N) s += deg[idx]; }
  sd[tid] = s; __syncthreads();
  for (int ofs=128; ofs>0; ofs>>=1){ if (tid<ofs) sd[tid]+=sd[tid+ofs]; __syncthreads(); }
  if (tid==0) part[blockIdx.x] = sd[0];
}

__global__ __launch_bounds__(256) void k_scan_final(const int* __restrict__ deg,
    const int* __restrict__ part, int* __restrict__ off, int N, int E)
{
  __shared__ int sc[256];
  int base = blockIdx.x*1024;
  int tid = threadIdx.x;
  int v[4]; int s = 0;
  #pragma unroll
  for (int i=0;i<4;++i){ int idx = base + tid*4 + i; v[i] = (idx<N)?deg[idx]:0; s += v[i]; }
  sc[tid] = s; __syncthreads();
  for (int ofs=1; ofs<256; ofs<<=1){
    int t = (tid>=ofs) ? sc[tid-ofs] : 0;
    __syncthreads();
    sc[tid] += t;
    __syncthreads();
  }
  int ex = sc[tid] - s + part[blockIdx.x];
  #pragma unroll
  for (int i=0;i<4;++i){
    int idx = base + tid*4 + i;
    if (idx < N){
      off[idx] = ex;
      if (idx == N-1) off[N] = ex + v[i];
      ex += v[i];
    }
  }
}

// place self edge (slot 0) + src ints at CSR positions
__global__ __launch_bounds__(256) void k_place(const int* __restrict__ bp,
    const int* __restrict__ bOff, const int* __restrict__ off,
    int* __restrict__ csr, int N)
{
  __shared__ int cur[BW];
  int tid = threadIdx.x;
  int b = blockIdx.x;
  int node0 = b << BSH;
  if (tid < BW){
    cur[tid] = 1;                                 // slot 0 reserved for self
    int node = node0 + tid;
    if (node < N) csr[off[node]] = node;
  }
  __syncthreads();
  int s = bOff[b], e = bOff[b+1];
  for (int i = s + tid; i < e; i += 256){
    int v  = bp[i];
    int dl = v & (BW-1);
    int sn = v >> BSH;
    int d  = node0 + dl;
    int p  = off[d] + atomicAdd(&cur[dl], 1);
    csr[p] = sn;
  }
}

// ---- canonicalize segment order (stable value-rank via shuffles) ----
__global__ __launch_bounds__(256) void k_rank(int* __restrict__ csr,
    const int* __restrict__ off, int N)
{
  int wid  = (blockIdx.x*256 + threadIdx.x) >> 6;
  int lane = threadIdx.x & 63;
  if (wid >= N) return;
  int s = off[wid], e = off[wid+1];
  int d = e - s;
  if (d <= 1) return;
  if (d <= 64){
    int v = (lane < d) ? csr[s+lane] : INT_MAX;
    int rank = 0;
    for (int j = 0; j < d; ++j){
      int bv = __shfl(v, j);
      rank += (bv < v) || (bv == v && j < lane);
    }
    if (lane < d) csr[s+rank] = v;
  } else if (d <= 256){
    int v0 = (lane      < d) ? csr[s+lane      ] : INT_MAX;
    int v1 = (lane+64   < d) ? csr[s+lane+64   ] : INT_MAX;
    int v2 = (lane+128  < d) ? csr[s+lane+128  ] : INT_MAX;
    int v3 = (lane+192  < d) ? csr[s+lane+192  ] : INT_MAX;
    int r0=0,r1=0,r2=0,r3=0;
    for (int j = 0; j < d; ++j){
      int slot = j >> 6, jl = j & 63;
      int bv = (slot==0) ? __shfl(v0,jl) : (slot==1) ? __shfl(v1,jl)
             : (slot==2) ? __shfl(v2,jl) : __shfl(v3,jl);
      r0 += (bv < v0) || (bv == v0 && j < lane);
      r1 += (bv < v1) || (bv == v1 && j < lane+64);
      r2 += (bv < v2) || (bv == v2 && j < lane+128);
      r3 += (bv < v3) || (bv == v3 && j < lane+192);
    }
    if (lane      < d) csr[s+r0]=v0;
    if (lane+64   < d) csr[s+r1]=v1;
    if (lane+128  < d) csr[s+r2]=v2;
    if (lane+192  < d) csr[s+r3]=v3;
  } else {
    if (lane == 0){
      for (int i = s+1; i < e; ++i){
        int key = csr[i]; int j = i-1;
        while (j >= s && csr[j] > key){ csr[j+1] = csr[j]; --j; }
        csr[j+1] = key;
      }
    }
  }
}

// ---- APPNP c-space iteration, bf16 state: 8 threads/node ----
// sub = tid&7: qh = sub>>2 (bf16 half-row: 8 classes = 16B), part = sub&3
// (edge quarter). Row = 16 bf16 = 32B -> 2 lane-requests/edge. fp32 accum.
// Deterministic: sorted csr, fixed quarter bounds, fixed combine order.
__global__ __launch_bounds__(256) void k_prop(const uint4* __restrict__ cin,
    const float* __restrict__ y0, const float* __restrict__ dinv2,
    uint4* __restrict__ cout,
    const int* __restrict__ csr, const int* __restrict__ off, int N)
{
  int t = blockIdx.x*256 + threadIdx.x;
  int n = t >> 3, sub = t & 7, qh = sub >> 2, part = sub & 3;
  if (n >= N) return;
  int s = off[n], e = off[n+1], d = e - s;
  int lo = s + ((d*part) >> 2);
  int hi = s + ((d*(part+1)) >> 2);
  float a[8] = {0.f,0.f,0.f,0.f,0.f,0.f,0.f,0.f};
  float b[8] = {0.f,0.f,0.f,0.f,0.f,0.f,0.f,0.f};
  int i = lo;
  for (; i+2 <= hi; i += 2){
    int s0 = csr[i], s1 = csr[i+1];
    uint4 u0 = cin[(size_t)s0*2 + qh];
    uint4 u1 = cin[(size_t)s1*2 + qh];
    a[0] += __uint_as_float(u0.x << 16); a[1] += __uint_as_float(u0.x & 0xFFFF0000u);
    a[2] += __uint_as_float(u0.y << 16); a[3] += __uint_as_float(u0.y & 0xFFFF0000u);
    a[4] += __uint_as_float(u0.z << 16); a[5] += __uint_as_float(u0.z & 0xFFFF0000u);
    a[6] += __uint_as_float(u0.w << 16); a[7] += __uint_as_float(u0.w & 0xFFFF0000u);
    b[0] += __uint_as_float(u1.x << 16); b[1] += __uint_as_float(u1.x & 0xFFFF0000u);
    b[2] += __uint_as_float(u1.y << 16); b[3] += __uint_as_float(u1.y & 0xFFFF0000u);
    b[4] += __uint_as_float(u1.z << 16); b[5] += __uint_as_float(u1.z & 0xFFFF0000u);
    b[6] += __uint_as_float(u1.w << 16); b[7] += __uint_as_float(u1.w & 0xFFFF0000u);
  }
  if (i < hi){
    uint4 u0 = cin[(size_t)csr[i]*2 + qh];
    a[0] += __uint_as_float(u0.x << 16); a[1] += __uint_as_float(u0.x & 0xFFFF0000u);
    a[2] += __uint_as_float(u0.y << 16); a[3] += __uint_as_float(u0.y & 0xFFFF0000u);
    a[4] += __uint_as_float(u0.z << 16); a[5] += __uint_as_float(u0.z & 0xFFFF0000u);
    a[6] += __uint_as_float(u0.w << 16); a[7] += __uint_as_float(u0.w & 0xFFFF0000u);
  }
  float v[8];
  #pragma unroll
  for (int j = 0; j < 8; ++j){
    float t2 = a[j] + b[j];
    t2 += __shfl_xor(t2, 1, 4);
    t2 += __shfl_xor(t2, 2, 4);
    v[j] = t2;
  }
  if (part == 0){
    float w9 = 0.9f * dinv2[n];
    const float4* y4 = (const float4*)y0;
    float4 ya = y4[(size_t)n*4 + qh*2];
    float4 yb = y4[(size_t)n*4 + qh*2 + 1];
    float o0 = fmaf(w9, v[0], ya.x), o1 = fmaf(w9, v[1], ya.y);
    float o2 = fmaf(w9, v[2], ya.z), o3 = fmaf(w9, v[3], ya.w);
    float o4 = fmaf(w9, v[4], yb.x), o5 = fmaf(w9, v[5], yb.y);
    float o6 = fmaf(w9, v[6], yb.z), o7 = fmaf(w9, v[7], yb.w);
    uint4 w;
    w.x = pack2bf_(o0, o1); w.y = pack2bf_(o2, o3);
    w.z = pack2bf_(o4, o5); w.w = pack2bf_(o6, o7);
    cout[(size_t)n*2 + qh] = w;
  }
}

// ---- last iteration fused with alpha/soft/argmax (8 threads/node) ----
__global__ __launch_bounds__(256) void k_prop_final(const uint4* __restrict__ cin,
    const float* __restrict__ x0, const float* __restrict__ dinv,
    const int* __restrict__ csr, const int* __restrict__ off,
    float* __restrict__ out, int N)
{
  int t = blockIdx.x*256 + threadIdx.x;
  int n = t >> 3, sub = t & 7, qh = sub >> 2, part = sub & 3;
  if (n >= N) return;
  int s = off[n], e = off[n+1], d = e - s;
  int lo = s + ((d*part) >> 2);
  int hi = s + ((d*(part+1)) >> 2);
  float a[8] = {0.f,0.f,0.f,0.f,0.f,0.f,0.f,0.f};
  float b[8] = {0.f,0.f,0.f,0.f,0.f,0.f,0.f,0.f};
  int i = lo;
  for (; i+2 <= hi; i += 2){
    int s0 = csr[i], s1 = csr[i+1];
    uint4 u0 = cin[(size_t)s0*2 + qh];
    uint4 u1 = cin[(size_t)s1*2 + qh];
    a[0] += __uint_as_float(u0.x << 16); a[1] += __uint_as_float(u0.x & 0xFFFF0000u);
    a[2] += __uint_as_float(u0.y << 16); a[3] += __uint_as_float(u0.y & 0xFFFF0000u);
    a[4] += __uint_as_float(u0.z << 16); a[5] += __uint_as_float(u0.z & 0xFFFF0000u);
    a[6] += __uint_as_float(u0.w << 16); a[7] += __uint_as_float(u0.w & 0xFFFF0000u);
    b[0] += __uint_as_float(u1.x << 16); b[1] += __uint_as_float(u1.x & 0xFFFF0000u);
    b[2] += __uint_as_float(u1.y << 16); b[3] += __uint_as_float(u1.y & 0xFFFF0000u);
    b[4] += __uint_as_float(u1.z << 16); b[5] += __uint_as_float(u1.z & 0xFFFF0000u);
    b[6] += __uint_as_float(u1.w << 16); b[7] += __uint_as_float(u1.w & 0xFFFF0000u);
  }
  if (i < hi){
    uint4 u0 = cin[(size_t)csr[i]*2 + qh];
    a[0] += __uint_as_float(u0.x << 16); a[1] += __uint_as_float(u0.x & 0xFFFF0000u);
    a[2] += __uint_as_float(u0.y << 16); a[3] += __uint_as_float(u0.y & 0xFFFF0000u);
    a[4] += __uint_as_float(u0.z << 16); a[5] += __uint_as_float(u0.z & 0xFFFF0000u);
    a[6] += __uint_as_float(u0.w << 16); a[7] += __uint_as_float(u0.w & 0xFFFF0000u);
  }
  float v[8];
  #pragma unroll
  for (int j = 0; j < 8; ++j){
    float t2 = a[j] + b[j];
    t2 += __shfl_xor(t2, 1, 4);
    t2 += __shfl_xor(t2, 2, 4);
    v[j] = t2;
  }
  if (part != 0) return;

  float w9 = 0.9f * dinv[n];
  const float4* x4 = (const float4*)x0;
  float4 xa = x4[(size_t)n*4 + qh*2];
  float4 xb = x4[(size_t)n*4 + qh*2 + 1];
  float xv[8] = {xa.x, xa.y, xa.z, xa.w, xb.x, xb.y, xb.z, xb.w};
  float al[8];
  #pragma unroll
  for (int j = 0; j < 8; ++j) al[j] = fmaf(w9, v[j], fmaf(0.1f, xv[j], 1.f));

  int nv = qh ? 2 : 8;              // qh0: classes 0-7, qh1: classes 8-9
  float sv = 0.f;
  for (int j = 0; j < nv; ++j) sv += al[j];
  sv += __shfl_xor(sv, 4, 8);

  float bv = -1e30f; int bi = 999;
  for (int j = 0; j < nv; ++j){
    if (al[j] > bv){ bv = al[j]; bi = qh*8 + j; }
  }
  {
    float vo = __shfl_xor(bv, 4, 8);
    int  io  = __shfl_xor(bi, 4, 8);
    if (vo > bv || (vo == bv && io < bi)){ bv = vo; bi = io; }
  }

  float inv = 1.0f / sv;
  size_t sb = (size_t)N + (size_t)n*NC;
  for (int j = 0; j < nv; ++j) out[sb + qh*8 + j] = al[j] * inv;
  if (sub == 0) out[n] = (float)bi;
}

extern "C" void kernel_launch(void* const* d_in, const int* in_sizes, int n_in,
                              void* d_out, int out_size, void* d_ws, size_t ws_size,
                              hipStream_t stream)
{
  const float* x  = (const float*)d_in[0];
  const int*   ei = (const int*)  d_in[1];
  const float* pc = (const float*)d_in[2];
  const float* W1 = (const float*)d_in[3];
  const float* b1 = (const float*)d_in[4];
  const float* W2 = (const float*)d_in[5];
  const float* b2 = (const float*)d_in[6];
  const float* z0 = (const float*)d_in[7];
  const float* ap = (const float*)d_in[8];
  const float* fb = (const float*)d_in[9];
  float* out = (float*)d_out;

  const int N = in_sizes[0] / DF;
  const int E = in_sizes[1] / 2;
  const int* src = ei;
  const int* dst = ei + E;
  const int B = (N + BW - 1) >> BSH;

  // Workspace. region0 holds bp (E ints) during CSR build, then z (N*16 f32).
  char* ws = (char*)d_ws;
  size_t o = 0;
  size_t region0 = (size_t)E*sizeof(int);
  if ((size_t)N*DL*sizeof(float) > region0) region0 = (size_t)N*DL*sizeof(float);
  int*   bp   = (int*)  (ws + o);
  float* z    = (float*)(ws + o);
  o += region0;
  int*   csr  = (int*)  (ws + o); o += (size_t)(E+N)*sizeof(int);   // +N self edges
  float* x0   = (float*)(ws + o); o += (size_t)N*DL*sizeof(float);
  float* y0   = (float*)(ws + o); o += (size_t)N*DL*sizeof(float);
  unsigned short* c0b = (unsigned short*)(ws + o); o += (size_t)N*DL*2;
  unsigned short* cAb = (unsigned short*)(ws + o); o += (size_t)N*DL*2;
  unsigned short* cBb = (unsigned short*)(ws + o); o += (size_t)N*DL*2;
  int*   deg  = (int*)  (ws + o); o += (size_t)N*sizeof(int);
  float* dinv = (float*)(ws + o); o += (size_t)N*sizeof(float);
  float* dinv2= (float*)(ws + o); o += (size_t)N*sizeof(float);
  int*   offs = (int*)  (ws + o); o += (size_t)(N+2)*sizeof(int);
  int*   part = (int*)  (ws + o); o += 4096;
  int*   bCnt = (int*)  (ws + o); o += MAXB*sizeof(int);
  int*   bOff = (int*)  (ws + o); o += (MAXB+1)*sizeof(int);
  int*   bCur = (int*)  (ws + o); o += MAXB*sizeof(int);

  const int TB = 256;
  int nb  = (N + 1023) / 1024;

  // Phase 1: bucketed CSR build (bp lives in region0)
  hipMemsetAsync(bCnt, 0, MAXB*sizeof(int), stream);
  hipMemsetAsync(bCur, 0, MAXB*sizeof(int), stream);
  k_bhist<<<512, TB, 0, stream>>>(dst, bCnt, E, B);
  k_scan_small<<<1, TB, 0, stream>>>(bCnt, bOff, B, 1);
  k_bscatter<<<(E + TILE - 1)/TILE, TB, 0, stream>>>(src, dst, bOff, bCur, bp, E, B);
  k_bdeg<<<B, TB, 0, stream>>>(bp, bOff, deg, dinv, dinv2, N);
  k_scan_part<<<nb, TB, 0, stream>>>(deg, part, N);
  k_scan_small<<<1, TB, 0, stream>>>(part, part, nb, 0);
  k_scan_final<<<nb, TB, 0, stream>>>(deg, part, offs, N, E);
  k_place<<<B, TB, 0, stream>>>(bp, bOff, offs, csr, N);
  k_rank<<<(N + 3) / 4, TB, 0, stream>>>(csr, offs, N);

  // Phase 2: encoder fused with z projection (z overwrites bp), then flows
  k_gemm1z<<<(N + BM - 1) / BM, TB, 0, stream>>>(x, W1, b1, W2, b2, z, N);
  k_flow2<<<((N*DL) + TB - 1) / TB, TB, 0, stream>>>(z, pc, z0, ap, fb, dinv,
                                                     x0, c0b, y0, N);

  // Phase 3: APPNP in bf16 c-space — 9 iterations + 1 fused, 8 thr/node
  int gP = ((N*8) + TB - 1) / TB;
  const unsigned short* cin = c0b;
  for (int it = 0; it < KPROP-1; ++it){
    unsigned short* cout = (it & 1) ? cBb : cAb;
    k_prop<<<gP, TB, 0, stream>>>((const uint4*)cin, y0, dinv2,
                                  (uint4*)cout, csr, offs, N);
    cin = cout;
  }
  k_prop_final<<<gP, TB, 0, stream>>>((const uint4*)cin, x0, dinv,
                                      csr, offs, out, N);
}